// Round 1
// baseline (262.780 us; speedup 1.0000x reference)
//
#include <hip/hip_runtime.h>
#include <stdint.h>

#define B_ 4
#define N_ 2048
#define H_ 16
#define D_ 64

typedef unsigned short u16;
typedef __attribute__((ext_vector_type(8))) short short8;
typedef __attribute__((ext_vector_type(16))) float f32x16;

__device__ __forceinline__ u16 f2bf(float f){
  union { float f; uint32_t u; } c; c.f = f;
  return (u16)((c.u + 0x7FFFu + ((c.u >> 16) & 1u)) >> 16);
}
__device__ __forceinline__ float bf2f(u16 b){
  union { uint32_t u; float f; } c; c.u = ((uint32_t)b) << 16;
  return c.f;
}
__device__ __forceinline__ uint32_t pack2(float a, float b){
  return (uint32_t)f2bf(a) | ((uint32_t)f2bf(b) << 16);
}
__device__ __forceinline__ void llds16(const void* g, void* l){
  __builtin_amdgcn_global_load_lds((const __attribute__((address_space(1))) void*)g,
                                   (__attribute__((address_space(3))) void*)l, 16, 0, 0);
}

// ---- repack: Q,K -> [B,H,N,64] bf16 (Q prescaled 1/8); V -> [B,H,64,N] bf16 ----
__global__ __launch_bounds__(256) void repack_qkv(const float* __restrict__ q,
    const float* __restrict__ k, const float* __restrict__ v,
    u16* __restrict__ Qb, u16* __restrict__ Kb, u16* __restrict__ VTb){
  const int row = blockIdx.x;            // b*N + n
  const int b = row >> 11, n = row & (N_-1);
  const int t = threadIdx.x;
  const float4 qv = ((const float4*)(q + (size_t)row*1024))[t];
  const float4 kv = ((const float4*)(k + (size_t)row*1024))[t];
  const float4 vv = ((const float4*)(v + (size_t)row*1024))[t];
  const float qa[4] = {qv.x,qv.y,qv.z,qv.w};
  const float ka[4] = {kv.x,kv.y,kv.z,kv.w};
  const float va[4] = {vv.x,vv.y,vv.z,vv.w};
#pragma unroll
  for (int u=0; u<4; ++u){
    const int c = 4*t+u, d = c>>4, h = c&15, bh = b*H_ + h;
    Qb[((size_t)bh*N_ + n)*D_ + d] = f2bf(qa[u]*0.125f);
    Kb[((size_t)bh*N_ + n)*D_ + d] = f2bf(ka[u]);
    VTb[((size_t)bh*D_ + d)*N_ + n] = f2bf(va[u]);
  }
}

// ---- repack bias -> transposed bf16: bT[m][n] = bias[n][m] ----
__global__ __launch_bounds__(256) void repack_biasT(const float* __restrict__ bias,
                                                    u16* __restrict__ bT){
  __shared__ float tile[64][65];
  const int bm = blockIdx.x & 31, bn = blockIdx.x >> 5;
  const int m0 = bm*64, n0 = bn*64, t = threadIdx.x;
#pragma unroll
  for (int kk=0; kk<16; ++kk){
    const int idx = t + kk*256, i = idx>>6, j = idx&63;
    tile[i][j] = bias[(size_t)(n0+i)*N_ + (m0+j)];
  }
  __syncthreads();
#pragma unroll
  for (int kk=0; kk<16; ++kk){
    const int idx = t + kk*256, r = idx>>6, c2 = idx&63;
    bT[(size_t)(m0+r)*N_ + (n0+c2)] = f2bf(tile[c2][r]);
  }
}

// swizzled LDS fragment read: 16B at (row, granule g), g XOR'd with row&7
__device__ __forceinline__ short8 ldsfrag(const u16* slab, int row, int g){
  return *(const short8*)(slab + row*64 + ((g ^ (row & 7)) << 3));
}

#define MFMA32(A,Bv,C) __builtin_amdgcn_mfma_f32_32x32x16_bf16(A,Bv,C,0,0,0)

// ---- flash attention, swapped orientation (S^T = K.Q^T, O^T = V^T.P^T) ----
// 8 waves: 2 heads x 4 strips of 32 q-rows. BK=64. lane&31 = q-row (n), lane>>5 = hi.
__global__ __launch_bounds__(512, 2) void attn_kernel(
    const u16* __restrict__ Qb, const u16* __restrict__ Kb,
    const u16* __restrict__ VTb, const u16* __restrict__ bT,
    float* __restrict__ out){
  __shared__ u16 K_sh[2*64*64];
  __shared__ u16 V_sh[2*64*64];

  const int tid = threadIdx.x;
  const int w = tid >> 6, lane = tid & 63;
  const int ln = lane & 31, hi = lane >> 5;
  const int bx = blockIdx.x;
  const int qt = bx & 15, hg = (bx>>4)&7, b = bx>>7;
  const int hs = w >> 2, strip = w & 3;
  const int bh = b*H_ + hg*2 + hs;
  const int nq = qt*128 + strip*32 + ln;

  // Q fragments (B-operand of S^T): lane holds Q[nq][kc*16 + hi*8 + j]
  short8 qf[4];
  {
    const u16* qb = Qb + ((size_t)bh*N_ + nq)*D_;
#pragma unroll
    for (int kc=0;kc<4;++kc) qf[kc] = *(const short8*)(qb + kc*16 + hi*8);
  }

  f32x16 O0, O1;
#pragma unroll
  for (int i=0;i<16;++i){ O0[i]=0.f; O1[i]=0.f; }
  float mrun = -__builtin_inff(), lrun = 0.f;

  const u16* Kslab = K_sh + hs*4096;
  const u16* Vslab = V_sh + hs*4096;
  const size_t Kg = (size_t)bh*N_*D_;
  const size_t Vg = (size_t)bh*D_*N_;
  const int r0b = strip*16;
  const int srow = lane >> 3, sb = lane & 7;

  for (int it=0; it<32; ++it){
    const int m0 = it*64;
    __syncthreads();
    // stage K rows m0..m0+63 and V^T rows (vd) 0..63, 16B/lane, pre-swizzled source
#pragma unroll
    for (int cc=0; cc<2; ++cc){
      const int r0 = r0b + cc*8;
      const int rowk = r0 + srow;
      llds16(Kb + Kg + (size_t)(m0+rowk)*D_ + ((sb ^ (rowk&7))<<3),
             (void*)(K_sh + hs*4096 + r0*64));
      llds16(VTb + Vg + (size_t)rowk*N_ + m0 + ((sb ^ (rowk&7))<<3),
             (void*)(V_sh + hs*4096 + r0*64));
    }
    __syncthreads();

    // score accumulators initialized with -bias[m][n] (C-init trick)
    f32x16 st0, st1;
    {
      const u16* bp = bT + (size_t)m0*N_ + (qt*128 + strip*32 + ln);
#pragma unroll
      for (int r=0;r<16;++r){
        const int ml = (r&3) + 8*(r>>2) + 4*hi;
        st0[r] = -bf2f(bp[(size_t)ml*N_]);
        st1[r] = -bf2f(bp[(size_t)(ml+32)*N_]);
      }
    }
#pragma unroll
    for (int kc=0;kc<4;++kc){
      const short8 k0 = ldsfrag(Kslab, ln,    kc*2 + hi);
      const short8 k1 = ldsfrag(Kslab, 32+ln, kc*2 + hi);
      st0 = MFMA32(k0, qf[kc], st0);
      st1 = MFMA32(k1, qf[kc], st1);
    }

    // online softmax over m; lane owns q-row n=ln, partner (lane^32) has other half of m
    float tmax = st0[0];
#pragma unroll
    for (int r=0;r<16;++r){ tmax = fmaxf(tmax, st0[r]); tmax = fmaxf(tmax, st1[r]); }
    tmax = fmaxf(tmax, __shfl_xor(tmax, 32));
    const float mnew = fmaxf(mrun, tmax);
    const float corr = __expf(mrun - mnew);
    float psum = 0.f;
#pragma unroll
    for (int r=0;r<16;++r){
      const float p0 = __expf(st0[r]-mnew); st0[r] = p0; psum += p0;
      const float p1 = __expf(st1[r]-mnew); st1[r] = p1; psum += p1;
    }
    psum += __shfl_xor(psum, 32);
    lrun = lrun*corr + psum;
    mrun = mnew;
#pragma unroll
    for (int r=0;r<16;++r){ O0[r] *= corr; O1[r] *= corr; }

    // PV: O^T += V^T . P^T  (P^T frags assembled in-register, one shfl_xor(32) pair per chunk)
#pragma unroll
    for (int mc=0;mc<4;++mc){
      uint32_t u0,u1,u2,u3;
      if (mc < 2){
        const int c8 = (mc&1)*8;
        u0 = pack2(st0[c8+0], st0[c8+1]);
        u1 = pack2(st0[c8+2], st0[c8+3]);
        u2 = pack2(st0[c8+4], st0[c8+5]);
        u3 = pack2(st0[c8+6], st0[c8+7]);
      } else {
        const int c8 = (mc&1)*8;
        u0 = pack2(st1[c8+0], st1[c8+1]);
        u1 = pack2(st1[c8+2], st1[c8+3]);
        u2 = pack2(st1[c8+4], st1[c8+5]);
        u3 = pack2(st1[c8+6], st1[c8+7]);
      }
      const uint32_t sx = hi ? u0 : u2;
      const uint32_t sy = hi ? u1 : u3;
      const uint32_t rx = (uint32_t)__shfl_xor((int)sx, 32);
      const uint32_t ry = (uint32_t)__shfl_xor((int)sy, 32);
      union { uint32_t u[4]; short8 s; } pf;
      pf.u[0] = hi ? rx : u0;
      pf.u[1] = hi ? ry : u1;
      pf.u[2] = hi ? u2 : rx;
      pf.u[3] = hi ? u3 : ry;
      const short8 v0 = ldsfrag(Vslab, ln,    mc*2 + hi);
      const short8 v1 = ldsfrag(Vslab, 32+ln, mc*2 + hi);
      O0 = MFMA32(v0, pf.s, O0);
      O1 = MFMA32(v1, pf.s, O1);
    }
  }

  const float inv = 1.0f / lrun;
  float* ob = out + ((size_t)bh*N_ + nq)*D_;
#pragma unroll
  for (int r=0;r<16;++r){
    const int vd = (r&3) + 8*(r>>2) + 4*hi;
    ob[vd]    = O0[r]*inv;
    ob[vd+32] = O1[r]*inv;
  }
}

extern "C" void kernel_launch(void* const* d_in, const int* in_sizes, int n_in,
                              void* d_out, int out_size, void* d_ws, size_t ws_size,
                              hipStream_t stream) {
  const float* q    = (const float*)d_in[0];
  const float* k    = (const float*)d_in[1];
  const float* v    = (const float*)d_in[2];
  const float* bias = (const float*)d_in[3];

  const size_t TEN = (size_t)B_*H_*N_*D_;   // 8,388,608 elems per tensor
  u16* Qb  = (u16*)d_ws;
  u16* Kb  = Qb + TEN;
  u16* VTb = Kb + TEN;
  u16* bTb = VTb + TEN;                     // + N*N = 4,194,304 elems

  repack_qkv<<<B_*N_, 256, 0, stream>>>(q, k, v, Qb, Kb, VTb);
  repack_biasT<<<1024, 256, 0, stream>>>(bias, bTb);
  attn_kernel<<<512, 512, 0, stream>>>(Qb, Kb, VTb, bTb, (float*)d_out);
}

// Round 3
// 205.245 us; speedup vs baseline: 1.2803x; 1.2803x over previous
//
#include <hip/hip_runtime.h>
#include <stdint.h>

#define B_ 4
#define N_ 2048
#define H_ 16
#define D_ 64
#define LOG2E 1.44269504088896f

typedef unsigned short u16;
typedef __attribute__((ext_vector_type(8))) short short8;
typedef __attribute__((ext_vector_type(16))) float f32x16;

#if __has_builtin(__builtin_amdgcn_exp2f)
#define EXP2(x) __builtin_amdgcn_exp2f(x)
#else
#define EXP2(x) exp2f(x)
#endif

__device__ __forceinline__ u16 f2bf(float f){
  union { float f; uint32_t u; } c; c.f = f;
  return (u16)((c.u + 0x7FFFu + ((c.u >> 16) & 1u)) >> 16);
}
__device__ __forceinline__ uint32_t cvtpk(float lo, float hi){
  uint32_t r; asm("v_cvt_pk_bf16_f32 %0, %1, %2" : "=v"(r) : "v"(lo), "v"(hi)); return r;
}
__device__ __forceinline__ void pl32swap(uint32_t &a, uint32_t &b){
  asm("v_permlane32_swap_b32 %0, %1" : "+v"(a), "+v"(b));
}
__device__ __forceinline__ void llds16(const void* g, void* l){
  __builtin_amdgcn_global_load_lds((const __attribute__((address_space(1))) void*)g,
                                   (__attribute__((address_space(3))) void*)l, 16, 0, 0);
}
// column swizzle for repack LDS tile (involution; apply PER ELEMENT)
__device__ __forceinline__ int csw(int c){ return c ^ ((c >> 6) << 1); }

// ---- repack: Q,K -> [B,H,N,64] bf16 (Q prescaled 0.125*log2e); V -> [B,H,64,N] bf16 ----
__global__ __launch_bounds__(256) void repack_qkv(const float* __restrict__ q,
    const float* __restrict__ k, const float* __restrict__ v,
    u16* __restrict__ Qb, u16* __restrict__ Kb, u16* __restrict__ VTb){
  __shared__ u16 tile[16][1026];
  const int blk = blockIdx.x;
  const int b = blk >> 7, nt = blk & 127;
  const int n0 = nt * 16;
  const int t = threadIdx.x;

  for (int pass = 0; pass < 3; ++pass){
    const float* src = pass==0 ? q : (pass==1 ? k : v);
    const float scale = (pass==0) ? 0.125f*LOG2E : 1.0f;
    if (pass) __syncthreads();
#pragma unroll
    for (int j = 0; j < 16; ++j){
      const float4 f = ((const float4*)(src + ((size_t)(b*N_ + n0 + j))*1024))[t];
      const int c = csw(4*t);
      // NOTE: 4t+u == 4t^u (u<4, 4t%4==0) and the XOR term of csw depends only
      // on bits>=6, so physical index of logical col 4t+u is c^u (NOT c+u).
      tile[j][c^0] = f2bf(f.x*scale); tile[j][c^1] = f2bf(f.y*scale);
      tile[j][c^2] = f2bf(f.z*scale); tile[j][c^3] = f2bf(f.w*scale);
    }
    __syncthreads();
    if (pass < 2){
      u16* dstT = (pass==0) ? Qb : Kb;
#pragma unroll
      for (int i2 = 0; i2 < 8; ++i2){
        const int id = t + i2*256;
        const int g = id & 7, nn = (id>>3) & 15, h = id >> 7;
        union { u16 b[8]; short8 s; } r8;
#pragma unroll
        for (int jj = 0; jj < 8; ++jj) r8.b[jj] = tile[nn][csw((g*8+jj)*16 + h)];
        *(short8*)(dstT + ((size_t)(b*H_+h)*N_ + n0+nn)*D_ + g*8) = r8.s;
      }
    } else {
#pragma unroll
      for (int i2 = 0; i2 < 8; ++i2){
        const int id = t + i2*256;
        const int gn = id & 1, d = (id>>1) & 63, h = id >> 7;
        union { u16 b[8]; short8 s; } r8;
#pragma unroll
        for (int jj = 0; jj < 8; ++jj) r8.b[jj] = tile[gn*8+jj][csw(d*16+h)];
        *(short8*)(VTb + ((size_t)(b*H_+h)*D_ + d)*N_ + n0 + gn*8) = r8.s;
      }
    }
  }
}

// ---- bias -> pre-packed f32 frag table: bPk[((mb*N+n)*2+hi)*32+r] = -log2e*bias[n][mb*64+ml(r,hi)]
__global__ __launch_bounds__(256) void repack_bias(const float* __restrict__ bias,
                                                   float* __restrict__ bPk){
  const int id = blockIdx.x*256 + threadIdx.x;       // 131072 threads
  const int hi = id & 1, n = (id>>1) & (N_-1), mb = id >> 12;
  const float* src = bias + (size_t)n*N_ + mb*64 + 4*hi;
  float4* dst = (float4*)(bPk + (size_t)id*32);
#pragma unroll
  for (int g2 = 0; g2 < 8; ++g2){
    float4 f = *(const float4*)(src + g2*8);
    dst[g2] = make_float4(-LOG2E*f.x, -LOG2E*f.y, -LOG2E*f.z, -LOG2E*f.w);
  }
}

// ---- flash attention, swapped orientation (S^T = K.Q^T, O^T = V^T.P^T) ----
// 4 waves = 4 strips of 32 q-rows, one (b,h) per block. BK=64, double-buffered LDS.
__global__ __launch_bounds__(256, 4) void attn_kernel(
    const u16* __restrict__ Qb, const u16* __restrict__ Kb,
    const u16* __restrict__ VTb, const float* __restrict__ bPk,
    float* __restrict__ out){
  __shared__ u16 K_sh[2*64*64];
  __shared__ u16 V_sh[2*64*64];

  const int tid = threadIdx.x;
  const int strip = tid >> 6, lane = tid & 63;
  const int ln = lane & 31, hi = lane >> 5;
  const int bx = blockIdx.x;
  // XCD-aware swizzle: 2 qt-groups per XCD -> bias slice is L2-resident
  const int xcd = bx & 7, ch = bx >> 3;
  const int qt = 2*xcd + (ch & 1);
  const int h  = (ch >> 1) & 15;
  const int b  = ch >> 5;
  const int bh = b*H_ + h;
  const int nq = qt*128 + strip*32 + ln;

  short8 qf[4];
  {
    const u16* qb = Qb + ((size_t)bh*N_ + nq)*D_;
#pragma unroll
    for (int kc = 0; kc < 4; ++kc) qf[kc] = *(const short8*)(qb + kc*16 + hi*8);
  }

  f32x16 O0, O1;
#pragma unroll
  for (int i = 0; i < 16; ++i){ O0[i] = 0.f; O1[i] = 0.f; }
  float mrun = -3.0e38f, lrun = 0.f;

  const size_t Kg = (size_t)bh*N_*D_;
  const size_t Vg = (size_t)bh*D_*N_;
  const int r0b = strip*16;
  const int srow = lane >> 3, sb = lane & 7;

  // prologue: stage tile 0 into buf 0
#pragma unroll
  for (int cc = 0; cc < 2; ++cc){
    const int r0 = r0b + cc*8;
    const int rowk = r0 + srow;
    llds16(Kb + Kg + (size_t)rowk*D_ + ((sb ^ (rowk&7))<<3), (void*)(K_sh + r0*64));
    llds16(VTb + Vg + (size_t)rowk*N_ + ((sb ^ (rowk&7))<<3), (void*)(V_sh + r0*64));
  }
  __syncthreads();

  for (int it = 0; it < 32; ++it){
    const int cur = it & 1;
    const u16* Kslab = K_sh + cur*4096;
    const u16* Vslab = V_sh + cur*4096;

    // stage next tile into the other buffer (drained by end-of-iter barrier)
    if (it < 31){
      const int m1 = (it+1)*64;
      u16* Kd = K_sh + (cur^1)*4096;
      u16* Vd = V_sh + (cur^1)*4096;
#pragma unroll
      for (int cc = 0; cc < 2; ++cc){
        const int r0 = r0b + cc*8;
        const int rowk = r0 + srow;
        llds16(Kb + Kg + (size_t)(m1+rowk)*D_ + ((sb ^ (rowk&7))<<3), (void*)(Kd + r0*64));
        llds16(VTb + Vg + (size_t)rowk*N_ + m1 + ((sb ^ (rowk&7))<<3), (void*)(Vd + r0*64));
      }
    }

    // C-init = -log2e * bias, loaded straight into the accumulator
    f32x16 st0, st1;
    {
      const float4* bp = (const float4*)(bPk + (((size_t)it*N_ + nq)*2 + hi)*32);
      float4 b0=bp[0],b1=bp[1],b2=bp[2],b3=bp[3],b4=bp[4],b5=bp[5],b6=bp[6],b7=bp[7];
      st0[0]=b0.x; st0[1]=b0.y; st0[2]=b0.z; st0[3]=b0.w;
      st0[4]=b1.x; st0[5]=b1.y; st0[6]=b1.z; st0[7]=b1.w;
      st0[8]=b2.x; st0[9]=b2.y; st0[10]=b2.z; st0[11]=b2.w;
      st0[12]=b3.x; st0[13]=b3.y; st0[14]=b3.z; st0[15]=b3.w;
      st1[0]=b4.x; st1[1]=b4.y; st1[2]=b4.z; st1[3]=b4.w;
      st1[4]=b5.x; st1[5]=b5.y; st1[6]=b5.z; st1[7]=b5.w;
      st1[8]=b6.x; st1[9]=b6.y; st1[10]=b6.z; st1[11]=b6.w;
      st1[12]=b7.x; st1[13]=b7.y; st1[14]=b7.z; st1[15]=b7.w;
    }
#pragma unroll
    for (int kc = 0; kc < 4; ++kc){
      const short8 k0 = *(const short8*)(Kslab + ln*64      + (((kc*2+hi) ^ (ln&7))<<3));
      const short8 k1 = *(const short8*)(Kslab + (32+ln)*64 + (((kc*2+hi) ^ ((32+ln)&7))<<3));
      st0 = __builtin_amdgcn_mfma_f32_32x32x16_bf16(k0, qf[kc], st0, 0,0,0);
      st1 = __builtin_amdgcn_mfma_f32_32x32x16_bf16(k1, qf[kc], st1, 0,0,0);
    }

    // tree max (depth 5)
    float tx[8];
#pragma unroll
    for (int j = 0; j < 8; ++j)
      tx[j] = fmaxf(fmaxf(st0[j], st0[j+8]), fmaxf(st1[j], st1[j+8]));
    float tmax = fmaxf(fmaxf(fmaxf(tx[0],tx[1]), fmaxf(tx[2],tx[3])),
                       fmaxf(fmaxf(tx[4],tx[5]), fmaxf(tx[6],tx[7])));
    tmax = fmaxf(tmax, __shfl_xor(tmax, 32));

    // defer-max: only rescale when max grew by > 8 (log2 units)
    if (!__all((int)(tmax - mrun <= 8.0f))){
      const float mnew = fmaxf(mrun, tmax);
      const float corr = EXP2(mrun - mnew);
      lrun *= corr;
#pragma unroll
      for (int r = 0; r < 16; ++r){ O0[r] *= corr; O1[r] *= corr; }
      mrun = mnew;
    }

    float ps0=0.f, ps1=0.f, ps2=0.f, ps3=0.f;
#pragma unroll
    for (int r = 0; r < 16; ++r){
      const float p0 = EXP2(st0[r] - mrun); st0[r] = p0;
      const float p1 = EXP2(st1[r] - mrun); st1[r] = p1;
      if (r & 1){ ps1 += p0; ps3 += p1; } else { ps0 += p0; ps2 += p1; }
    }
    float psum = (ps0 + ps1) + (ps2 + ps3);
    psum += __shfl_xor(psum, 32);
    lrun += psum;

    // PV: P->bf16 via cvt_pk, cross-half exchange via permlane32_swap
#pragma unroll
    for (int mc = 0; mc < 4; ++mc){
      const int c8 = (mc & 1)*8;
      uint32_t u0,u1,u2,u3;
      if (mc < 2){
        u0 = cvtpk(st0[c8+0], st0[c8+1]); u1 = cvtpk(st0[c8+2], st0[c8+3]);
        u2 = cvtpk(st0[c8+4], st0[c8+5]); u3 = cvtpk(st0[c8+6], st0[c8+7]);
      } else {
        u0 = cvtpk(st1[c8+0], st1[c8+1]); u1 = cvtpk(st1[c8+2], st1[c8+3]);
        u2 = cvtpk(st1[c8+4], st1[c8+5]); u3 = cvtpk(st1[c8+6], st1[c8+7]);
      }
      pl32swap(u0, u2); pl32swap(u1, u3);
      union { uint32_t u[4]; short8 s; } pf;
      pf.u[0]=u0; pf.u[1]=u1; pf.u[2]=u2; pf.u[3]=u3;
      const short8 v0 = *(const short8*)(Vslab + ln*64      + (((mc*2+hi) ^ (ln&7))<<3));
      const short8 v1 = *(const short8*)(Vslab + (32+ln)*64 + (((mc*2+hi) ^ ((32+ln)&7))<<3));
      O0 = __builtin_amdgcn_mfma_f32_32x32x16_bf16(v0, pf.s, O0, 0,0,0);
      O1 = __builtin_amdgcn_mfma_f32_32x32x16_bf16(v1, pf.s, O1, 0,0,0);
    }
    __syncthreads();
  }

  const float inv = 1.0f / lrun;
  float* ob = out + ((size_t)bh*N_ + nq)*D_;
#pragma unroll
  for (int g2 = 0; g2 < 4; ++g2){
    float4 a = make_float4(O0[4*g2]*inv, O0[4*g2+1]*inv, O0[4*g2+2]*inv, O0[4*g2+3]*inv);
    float4 c = make_float4(O1[4*g2]*inv, O1[4*g2+1]*inv, O1[4*g2+2]*inv, O1[4*g2+3]*inv);
    *(float4*)(ob + 8*g2 + 4*hi)      = a;
    *(float4*)(ob + 8*g2 + 4*hi + 32) = c;
  }
}

extern "C" void kernel_launch(void* const* d_in, const int* in_sizes, int n_in,
                              void* d_out, int out_size, void* d_ws, size_t ws_size,
                              hipStream_t stream) {
  const float* q    = (const float*)d_in[0];
  const float* k    = (const float*)d_in[1];
  const float* v    = (const float*)d_in[2];
  const float* bias = (const float*)d_in[3];

  const size_t TEN = (size_t)B_*H_*N_*D_;   // 8,388,608 elems per tensor
  u16* Qb  = (u16*)d_ws;
  u16* Kb  = Qb + TEN;
  u16* VTb = Kb + TEN;
  float* bPk = (float*)(VTb + TEN);         // 4,194,304 floats (16 MB)

  repack_qkv<<<B_*128, 256, 0, stream>>>(q, k, v, Qb, Kb, VTb);
  repack_bias<<<512, 256, 0, stream>>>(bias, bPk);
  attn_kernel<<<1024, 256, 0, stream>>>(Qb, Kb, VTb, bPk, (float*)d_out);
}

// Round 5
// 194.186 us; speedup vs baseline: 1.3532x; 1.0570x over previous
//
#include <hip/hip_runtime.h>
#include <stdint.h>

#define B_ 4
#define N_ 2048
#define H_ 16
#define D_ 64
#define LOG2E 1.44269504088896f

typedef unsigned short u16;
typedef __attribute__((ext_vector_type(8))) short short8;
typedef __attribute__((ext_vector_type(16))) float f32x16;

#if __has_builtin(__builtin_amdgcn_exp2f)
#define EXP2(x) __builtin_amdgcn_exp2f(x)
#else
#define EXP2(x) exp2f(x)
#endif

__device__ __forceinline__ u16 f2bf(float f){
  union { float f; uint32_t u; } c; c.f = f;
  return (u16)((c.u + 0x7FFFu + ((c.u >> 16) & 1u)) >> 16);
}
__device__ __forceinline__ uint32_t cvtpk(float lo, float hi){
  uint32_t r; asm("v_cvt_pk_bf16_f32 %0, %1, %2" : "=v"(r) : "v"(lo), "v"(hi)); return r;
}
__device__ __forceinline__ void pl32swap(uint32_t &a, uint32_t &b){
  asm("v_permlane32_swap_b32 %0, %1" : "+v"(a), "+v"(b));
}
__device__ __forceinline__ void llds16(const void* g, void* l){
  __builtin_amdgcn_global_load_lds((const __attribute__((address_space(1))) void*)g,
                                   (__attribute__((address_space(3))) void*)l, 16, 0, 0);
}
// column swizzle for repack LDS tile (involution; apply PER ELEMENT)
__device__ __forceinline__ int csw(int c){ return c ^ ((c >> 6) << 1); }

// ---- repack: Q,K -> [B,H,N,64] bf16 (Q prescaled 0.125*log2e); V -> [B,H,64,N] bf16 ----
__global__ __launch_bounds__(256) void repack_qkv(const float* __restrict__ q,
    const float* __restrict__ k, const float* __restrict__ v,
    u16* __restrict__ Qb, u16* __restrict__ Kb, u16* __restrict__ VTb){
  __shared__ u16 tile[16][1026];
  const int blk = blockIdx.x;
  const int b = blk >> 7, nt = blk & 127;
  const int n0 = nt * 16;
  const int t = threadIdx.x;

  for (int pass = 0; pass < 3; ++pass){
    const float* src = pass==0 ? q : (pass==1 ? k : v);
    const float scale = (pass==0) ? 0.125f*LOG2E : 1.0f;
    if (pass) __syncthreads();
#pragma unroll
    for (int j = 0; j < 16; ++j){
      const float4 f = ((const float4*)(src + ((size_t)(b*N_ + n0 + j))*1024))[t];
      const int c = csw(4*t);
      // physical index of logical col 4t+u is c^u (XOR term of csw is in bits>=6)
      tile[j][c^0] = f2bf(f.x*scale); tile[j][c^1] = f2bf(f.y*scale);
      tile[j][c^2] = f2bf(f.z*scale); tile[j][c^3] = f2bf(f.w*scale);
    }
    __syncthreads();
    if (pass < 2){
      u16* dstT = (pass==0) ? Qb : Kb;
#pragma unroll
      for (int i2 = 0; i2 < 8; ++i2){
        const int id = t + i2*256;
        const int g = id & 7, nn = (id>>3) & 15, h = id >> 7;
        union { u16 b[8]; short8 s; } r8;
#pragma unroll
        for (int jj = 0; jj < 8; ++jj) r8.b[jj] = tile[nn][csw((g*8+jj)*16 + h)];
        *(short8*)(dstT + ((size_t)(b*H_+h)*N_ + n0+nn)*D_ + g*8) = r8.s;
      }
    } else {
#pragma unroll
      for (int i2 = 0; i2 < 8; ++i2){
        const int id = t + i2*256;
        const int gn = id & 1, d = (id>>1) & 63, h = id >> 7;
        union { u16 b[8]; short8 s; } r8;
#pragma unroll
        for (int jj = 0; jj < 8; ++jj) r8.b[jj] = tile[gn*8+jj][csw(d*16+h)];
        *(short8*)(VTb + ((size_t)(b*H_+h)*D_ + d)*N_ + n0 + gn*8) = r8.s;
      }
    }
  }
}

// ---- bias -> pre-packed bf16 frag table:
// bB[(((mb*N)+n)*2+hi)*32 + j] = bf16(-log2e * bias[n][mb*64 + 4*hi + (j>>2)*8 + (j&3)])
__global__ __launch_bounds__(256) void repack_biasb(const float* __restrict__ bias,
                                                    u16* __restrict__ bB){
  const int id = blockIdx.x*256 + threadIdx.x;       // 131072 threads
  const int hi = id & 1, n = (id>>1) & (N_-1), mb = id >> 12;
  const float* src = bias + (size_t)n*N_ + mb*64 + 4*hi;
  uint32_t w[16];
#pragma unroll
  for (int g2 = 0; g2 < 8; ++g2){
    float4 f = *(const float4*)(src + g2*8);
    w[2*g2+0] = cvtpk(-LOG2E*f.x, -LOG2E*f.y);
    w[2*g2+1] = cvtpk(-LOG2E*f.z, -LOG2E*f.w);
  }
  uint4* dst = (uint4*)(bB + (size_t)id*32);
#pragma unroll
  for (int g4 = 0; g4 < 4; ++g4)
    dst[g4] = make_uint4(w[4*g4], w[4*g4+1], w[4*g4+2], w[4*g4+3]);
}

// ---- flash attention, swapped orientation (S^T = K.Q^T, O^T = V^T.P^T) ----
// 4 waves = 4 strips of 32 q-rows, one (b,h) per block. BK=64, double-buffered LDS,
// bias frags register-prefetched one iteration ahead.
__global__ __launch_bounds__(256, 4) void attn_kernel(
    const u16* __restrict__ Qb, const u16* __restrict__ Kb,
    const u16* __restrict__ VTb, const u16* __restrict__ bB,
    float* __restrict__ out){
  __shared__ u16 K_sh[2*64*64];
  __shared__ u16 V_sh[2*64*64];

  const int tid = threadIdx.x;
  const int strip = tid >> 6, lane = tid & 63;
  const int ln = lane & 31, hi = lane >> 5;
  const int bx = blockIdx.x;
  // XCD-aware swizzle: 2 qt-groups per XCD -> bias slice is L2-resident
  const int xcd = bx & 7, ch = bx >> 3;
  const int qt = 2*xcd + (ch & 1);
  const int h  = (ch >> 1) & 15;
  const int b  = ch >> 5;
  const int bh = b*H_ + h;
  const int nq = qt*128 + strip*32 + ln;

  short8 qf[4];
  {
    const u16* qb = Qb + ((size_t)bh*N_ + nq)*D_;
#pragma unroll
    for (int kc = 0; kc < 4; ++kc) qf[kc] = *(const short8*)(qb + kc*16 + hi*8);
  }

  f32x16 O0, O1;
#pragma unroll
  for (int i = 0; i < 16; ++i){ O0[i] = 0.f; O1[i] = 0.f; }
  float mrun = -3.0e38f, lrun = 0.f;

  const size_t Kg = (size_t)bh*N_*D_;
  const size_t Vg = (size_t)bh*D_*N_;
  const int r0b = strip*16;
  const int srow = lane >> 3, sb = lane & 7;
  const size_t bBbase = ((size_t)nq*2 + hi)*32;   // + it*N*64 per iter

  // prologue: stage tile 0 into buf 0; prefetch bias frags for iter 0
  uint32_t bn[16];
#pragma unroll
  for (int cc = 0; cc < 2; ++cc){
    const int r0 = r0b + cc*8;
    const int rowk = r0 + srow;
    llds16(Kb + Kg + (size_t)rowk*D_ + ((sb ^ (rowk&7))<<3), (void*)(K_sh + r0*64));
    llds16(VTb + Vg + (size_t)rowk*N_ + ((sb ^ (rowk&7))<<3), (void*)(V_sh + r0*64));
  }
  {
    const uint4* bp = (const uint4*)(bB + bBbase);
#pragma unroll
    for (int g4 = 0; g4 < 4; ++g4){
      uint4 qv = bp[g4];
      bn[4*g4]=qv.x; bn[4*g4+1]=qv.y; bn[4*g4+2]=qv.z; bn[4*g4+3]=qv.w;
    }
  }
  __syncthreads();

#pragma unroll 2
  for (int it = 0; it < 32; ++it){
    const int cur = it & 1;
    const u16* Kslab = K_sh + cur*4096;
    const u16* Vslab = V_sh + cur*4096;

    // stage next K/V tile into the other buffer (drained by end-of-iter barrier)
    if (it < 31){
      const int m1 = (it+1)*64;
      u16* Kd = K_sh + (cur^1)*4096;
      u16* Vd = V_sh + (cur^1)*4096;
#pragma unroll
      for (int cc = 0; cc < 2; ++cc){
        const int r0 = r0b + cc*8;
        const int rowk = r0 + srow;
        llds16(Kb + Kg + (size_t)(m1+rowk)*D_ + ((sb ^ (rowk&7))<<3), (void*)(Kd + r0*64));
        llds16(VTb + Vg + (size_t)rowk*N_ + m1 + ((sb ^ (rowk&7))<<3), (void*)(Vd + r0*64));
      }
    }

    // C-init from the prefetched bias registers (pure VALU, no memory wait)
    f32x16 st0, st1;
#pragma unroll
    for (int k2 = 0; k2 < 8; ++k2){
      st0[2*k2]   = __uint_as_float(bn[k2]   << 16);
      st0[2*k2+1] = __uint_as_float(bn[k2]   & 0xffff0000u);
      st1[2*k2]   = __uint_as_float(bn[k2+8] << 16);
      st1[2*k2+1] = __uint_as_float(bn[k2+8] & 0xffff0000u);
    }
    // prefetch next iteration's bias frags (consumed after next barrier)
    if (it < 31){
      const uint4* bp = (const uint4*)(bB + (size_t)(it+1)*N_*64 + bBbase);
#pragma unroll
      for (int g4 = 0; g4 < 4; ++g4){
        uint4 qv = bp[g4];
        bn[4*g4]=qv.x; bn[4*g4+1]=qv.y; bn[4*g4+2]=qv.z; bn[4*g4+3]=qv.w;
      }
    }

#pragma unroll
    for (int kc = 0; kc < 4; ++kc){
      const short8 k0 = *(const short8*)(Kslab + ln*64      + (((kc*2+hi) ^ (ln&7))<<3));
      const short8 k1 = *(const short8*)(Kslab + (32+ln)*64 + (((kc*2+hi) ^ ((32+ln)&7))<<3));
      st0 = __builtin_amdgcn_mfma_f32_32x32x16_bf16(k0, qf[kc], st0, 0,0,0);
      st1 = __builtin_amdgcn_mfma_f32_32x32x16_bf16(k1, qf[kc], st1, 0,0,0);
    }

    // tree max (depth 5) + cross-half combine (shfl_xor: proven in R3)
    float tx[8];
#pragma unroll
    for (int j = 0; j < 8; ++j)
      tx[j] = fmaxf(fmaxf(st0[j], st0[j+8]), fmaxf(st1[j], st1[j+8]));
    float tmax = fmaxf(fmaxf(fmaxf(tx[0],tx[1]), fmaxf(tx[2],tx[3])),
                       fmaxf(fmaxf(tx[4],tx[5]), fmaxf(tx[6],tx[7])));
    tmax = fmaxf(tmax, __shfl_xor(tmax, 32));

    // defer-max: only rescale when max grew by > 8 (log2 units)
    if (!__all((int)(tmax - mrun <= 8.0f))){
      const float mnew = fmaxf(mrun, tmax);
      const float corr = EXP2(mrun - mnew);
      lrun *= corr;
#pragma unroll
      for (int r = 0; r < 16; ++r){ O0[r] *= corr; O1[r] *= corr; }
      mrun = mnew;
    }

    float ps0=0.f, ps1=0.f, ps2=0.f, ps3=0.f;
#pragma unroll
    for (int r = 0; r < 16; ++r){
      const float p0 = EXP2(st0[r] - mrun); st0[r] = p0;
      const float p1 = EXP2(st1[r] - mrun); st1[r] = p1;
      if (r & 1){ ps1 += p0; ps3 += p1; } else { ps0 += p0; ps2 += p1; }
    }
    float psum = (ps0 + ps1) + (ps2 + ps3);
    psum += __shfl_xor(psum, 32);
    lrun += psum;

    // PV: P->bf16 via cvt_pk, cross-half exchange via permlane32_swap
#pragma unroll
    for (int mc = 0; mc < 4; ++mc){
      const int c8 = (mc & 1)*8;
      uint32_t u0,u1,u2,u3;
      if (mc < 2){
        u0 = cvtpk(st0[c8+0], st0[c8+1]); u1 = cvtpk(st0[c8+2], st0[c8+3]);
        u2 = cvtpk(st0[c8+4], st0[c8+5]); u3 = cvtpk(st0[c8+6], st0[c8+7]);
      } else {
        u0 = cvtpk(st1[c8+0], st1[c8+1]); u1 = cvtpk(st1[c8+2], st1[c8+3]);
        u2 = cvtpk(st1[c8+4], st1[c8+5]); u3 = cvtpk(st1[c8+6], st1[c8+7]);
      }
      pl32swap(u0, u2); pl32swap(u1, u3);
      union { uint32_t u[4]; short8 s; } pf;
      pf.u[0]=u0; pf.u[1]=u1; pf.u[2]=u2; pf.u[3]=u3;
      const short8 v0 = *(const short8*)(Vslab + ln*64      + (((mc*2+hi) ^ (ln&7))<<3));
      const short8 v1 = *(const short8*)(Vslab + (32+ln)*64 + (((mc*2+hi) ^ ((32+ln)&7))<<3));
      O0 = __builtin_amdgcn_mfma_f32_32x32x16_bf16(v0, pf.s, O0, 0,0,0);
      O1 = __builtin_amdgcn_mfma_f32_32x32x16_bf16(v1, pf.s, O1, 0,0,0);
    }
    __syncthreads();
  }

  const float inv = 1.0f / lrun;
  float* ob = out + ((size_t)bh*N_ + nq)*D_;
#pragma unroll
  for (int g2 = 0; g2 < 4; ++g2){
    float4 a = make_float4(O0[4*g2]*inv, O0[4*g2+1]*inv, O0[4*g2+2]*inv, O0[4*g2+3]*inv);
    float4 c = make_float4(O1[4*g2]*inv, O1[4*g2+1]*inv, O1[4*g2+2]*inv, O1[4*g2+3]*inv);
    *(float4*)(ob + 8*g2 + 4*hi)      = a;
    *(float4*)(ob + 8*g2 + 4*hi + 32) = c;
  }
}

extern "C" void kernel_launch(void* const* d_in, const int* in_sizes, int n_in,
                              void* d_out, int out_size, void* d_ws, size_t ws_size,
                              hipStream_t stream) {
  const float* q    = (const float*)d_in[0];
  const float* k    = (const float*)d_in[1];
  const float* v    = (const float*)d_in[2];
  const float* bias = (const float*)d_in[3];

  const size_t TEN = (size_t)B_*H_*N_*D_;   // 8,388,608 elems per tensor
  u16* Qb  = (u16*)d_ws;
  u16* Kb  = Qb + TEN;
  u16* VTb = Kb + TEN;
  u16* bB  = VTb + TEN;                     // 4,194,304 u16 (8 MB)

  repack_qkv<<<B_*128, 256, 0, stream>>>(q, k, v, Qb, Kb, VTb);
  repack_biasb<<<512, 256, 0, stream>>>(bias, bB);
  attn_kernel<<<1024, 256, 0, stream>>>(Qb, Kb, VTb, bB, (float*)d_out);
}